// Round 6
// baseline (98.182 us; speedup 1.0000x reference)
//
#include <hip/hip_runtime.h>
#include <cfloat>
#include <stdint.h>

#define B_ 16
#define N_ 4096
#define M_ 1024
#define EPS_ 1e-12f

__device__ __forceinline__ uint32_t umin3(uint32_t a, uint32_t b, uint32_t c) {
    return min(a, min(b, c));                    // -> v_min3_u32
}
__device__ __forceinline__ uint32_t umed3(uint32_t a, uint32_t b, uint32_t c) {
    return max(min(a, b), min(max(a, b), c));    // -> v_med3_u32
}

// Uniform fused kernel: 2048 identical blocks (16 b x 128 tiles), no role
// imbalance. Each block does BOTH:
//   Part A (cd1, 32 points): s=tid&7 m-split, g=tid>>3 owns 1 point.
//     LDS: skel float4[x,y,z,|s|^2]. Per 2 pairs: 6 fma + v_min3_f32 on
//     t = |s|^2 - 2 p.s (|p|^2 added post-min; monotone).
//   Part B (knn -> cd2+normal, 8 m): s=tid&63 full-wave n-split, wave w owns
//     2 m-chains. LDS reused: pts float4 staged in 4x1024 phases. Per 2
//     pairs/chain: 2 add + 6 fma + 2 v_and_or + med3 + min3 + min on packed
//     keys (bits(d^2)&~0xFFF)|n  (d^2>=0 -> uint order == float order; low
//     12 bits break ties toward smaller n like top_k). Exact distance
//     recomputed for winners in the epilogue.
__global__ __launch_bounds__(256, 8) void fused_kernel(const float* __restrict__ shape_xyz,
                                                       const float* __restrict__ skel_xyz,
                                                       const float* __restrict__ skel_nori,
                                                       float* __restrict__ out)
{
    __shared__ float4 ls4[1024];   // 16 KB, reused by both parts
    __shared__ float ws[4];

    const int b = blockIdx.x >> 7;       // 0..15
    const int t = blockIdx.x & 127;      // tile within b

    float v = 0.0f;

    // ================= Part A: cd1 for points t*32 .. t*32+31 =================
    const float* skb = skel_xyz + (size_t)b * M_ * 3;
    for (int i = threadIdx.x; i < 1024; i += 256) {
        const float x = skb[i * 3 + 0];
        const float y = skb[i * 3 + 1];
        const float z = skb[i * 3 + 2];
        ls4[i] = make_float4(x, y, z, fmaf(x, x, fmaf(y, y, z * z)));
    }
    __syncthreads();

    {
        const int sA = threadIdx.x & 7;
        const int gA = threadIdx.x >> 3;           // 0..31
        const float* p = shape_xyz + ((size_t)b * N_ + t * 32 + gA) * 6;
        const float px = p[0], py = p[1], pz = p[2];
        const float m2x = -2.0f * px, m2y = -2.0f * py, m2z = -2.0f * pz;
        const float pp  = fmaf(px, px, fmaf(py, py, pz * pz));

        float best = FLT_MAX;
#pragma unroll 4
        for (int j = 0; j < 64; ++j) {             // 2 m per iter
            const float4 s0 = ls4[j * 16 + sA];
            const float4 s1 = ls4[j * 16 + 8 + sA];
            const float t0 = fmaf(m2x, s0.x, fmaf(m2y, s0.y, fmaf(m2z, s0.z, s0.w)));
            const float t1 = fmaf(m2x, s1.x, fmaf(m2y, s1.y, fmaf(m2z, s1.z, s1.w)));
            best = fminf(best, fminf(t0, t1));     // -> v_min3_f32
        }
#pragma unroll
        for (int off = 1; off < 8; off <<= 1) best = fminf(best, __shfl_xor(best, off));
        if (sA == 0) v += sqrtf(fmaxf(best + pp, EPS_)) * 1e-4f;
    }

    // ================= Part B: knn for m = t*8 .. t*8+7 =================
    const int sB = threadIdx.x & 63;               // full-wave n-split
    const int w  = threadIdx.x >> 6;               // wave 0..3
    const int m0 = t * 8 + w * 2;                  // 2 chains per lane

    float m2x[2], m2y[2], m2z[2], aa[2];
    uint32_t k1[2], k2[2];
    {
        const float* sq = skel_xyz + ((size_t)b * M_ + m0) * 3;
#pragma unroll
        for (int c = 0; c < 2; ++c) {
            const float x = sq[c * 3 + 0];
            const float y = sq[c * 3 + 1];
            const float z = sq[c * 3 + 2];
            m2x[c] = -2.0f * x; m2y[c] = -2.0f * y; m2z[c] = -2.0f * z;
            aa[c]  = fmaf(x, x, fmaf(y, y, z * z));
            k1[c] = 0xFFFFFFFFu; k2[c] = 0xFFFFFFFFu;
        }
    }

    const uint32_t HI = 0xFFFFF000u;
    const float* sb = shape_xyz + (size_t)b * N_ * 6;

    for (int ph = 0; ph < 4; ++ph) {
        __syncthreads();                           // previous ls4 contents fully read
        for (int i = threadIdx.x; i < 1024; i += 256) {
            const float* pt = sb + (size_t)(ph * 1024 + i) * 6;
            const float x = pt[0], y = pt[1], z = pt[2];
            ls4[i] = make_float4(x, y, z, fmaf(x, x, fmaf(y, y, z * z)));
        }
        __syncthreads();
        const uint32_t nb = (uint32_t)(ph * 1024);

#pragma unroll 2
        for (int j = 0; j < 8; ++j) {              // 2 points per iter
            const int nl = j * 128 + sB;
            const float4 qA = ls4[nl];
            const float4 qB = ls4[nl + 64];
            const uint32_t gnA = nb + (uint32_t)nl;
            const uint32_t gnB = gnA + 64u;
#pragma unroll
            for (int c = 0; c < 2; ++c) {
                const float tA = fmaf(m2x[c], qA.x, fmaf(m2y[c], qA.y, fmaf(m2z[c], qA.z, qA.w + aa[c])));
                const float tB = fmaf(m2x[c], qB.x, fmaf(m2y[c], qB.y, fmaf(m2z[c], qB.z, qB.w + aa[c])));
                const uint32_t kA = (__float_as_uint(tA) & HI) | gnA;
                const uint32_t kB = (__float_as_uint(tB) & HI) | gnB;
                k2[c] = min(k2[c], umed3(k1[c], kA, kB));
                k1[c] = umin3(k1[c], kA, kB);
            }
        }
    }

    // butterfly top-2 merge across all 64 lanes
#pragma unroll
    for (int off = 1; off < 64; off <<= 1) {
#pragma unroll
        for (int c = 0; c < 2; ++c) {
            const uint32_t o1 = (uint32_t)__shfl_xor((int)k1[c], off);
            const uint32_t o2 = (uint32_t)__shfl_xor((int)k2[c], off);
            const uint32_t nk2 = min(min(k2[c], o2), max(k1[c], o1));
            k1[c] = min(k1[c], o1);
            k2[c] = nk2;
        }
    }

    if (sB == 0) {
        const float* no = skel_nori + ((size_t)b * M_ + m0) * 3;
        const float kN = 0.001f * 0.5f / (float)B_;
#pragma unroll
        for (int c = 0; c < 2; ++c) {
            const int i1 = (int)(k1[c] & 0xFFFu);
            const int i2 = (int)(k2[c] & 0xFFFu);
            const float* p1 = sb + (size_t)i1 * 6;
            const float* p2 = sb + (size_t)i2 * 6;
            // exact nearest distance (removes key quantization from cd2)
            const float ax = -0.5f * m2x[c], ay = -0.5f * m2y[c], az = -0.5f * m2z[c];
            const float dx = ax - p1[0], dy = ay - p1[1], dz = az - p1[2];
            const float d2 = fmaf(dx, dx, fmaf(dy, dy, dz * dz));
            const float q0 = no[c * 3 + 0], q1 = no[c * 3 + 1], q2 = no[c * 3 + 2];
            const float dot1 = q0 * p1[3] + q1 * p1[4] + q2 * p1[5];
            const float dot2 = q0 * p2[3] + q1 * p2[4] + q2 * p2[5];
            v += sqrtf(fmaxf(d2, EPS_)) * 1e-4f + (fabsf(dot1) + fabsf(dot2)) * kN;
        }
    }

    // block reduction + one atomic per block
#pragma unroll
    for (int off = 32; off > 0; off >>= 1) v += __shfl_down(v, off);
    if ((threadIdx.x & 63) == 0) ws[threadIdx.x >> 6] = v;
    __syncthreads();
    if (threadIdx.x == 0) atomicAdd(out, ws[0] + ws[1] + ws[2] + ws[3]);
}

extern "C" void kernel_launch(void* const* d_in, const int* in_sizes, int n_in,
                              void* d_out, int out_size, void* d_ws, size_t ws_size,
                              hipStream_t stream) {
    const float* shape_xyz = (const float*)d_in[0];  // (16, 4096, 6)
    const float* skel_xyz  = (const float*)d_in[1];  // (16, 1024, 3)
    const float* skel_nori = (const float*)d_in[2];  // (16, 1024, 3)
    float* out = (float*)d_out;                      // scalar

    hipMemsetAsync(out, 0, sizeof(float), stream);   // d_out poisoned each call
    fused_kernel<<<2048, 256, 0, stream>>>(shape_xyz, skel_xyz, skel_nori, out);
}

// Round 7
// 87.461 us; speedup vs baseline: 1.1226x; 1.1226x over previous
//
#include <hip/hip_runtime.h>
#include <cfloat>
#include <stdint.h>

#define B_ 16
#define N_ 4096
#define M_ 1024
#define EPS_ 1e-12f

__device__ __forceinline__ uint32_t umin3(uint32_t a, uint32_t b, uint32_t c) {
    return min(a, min(b, c));                    // -> v_min3_u32
}
__device__ __forceinline__ uint32_t umed3(uint32_t a, uint32_t b, uint32_t c) {
    return max(min(a, b), min(max(a, b), c));    // -> v_med3_u32
}

// 1536 blocks, work-matched roles (~1750 VALU ops/lane each), 6 blocks/CU.
// blocks [0,512):   cd1 for 128 points each. sA=tid&15 m-split, gA=tid>>4
//   owns 8 points. Per 2 pairs: 6 fma + v_min3_f32 on t = |s|^2 - 2 p.s
//   (|p|^2 added post-min; monotone). Skel staged as float4[x,y,z,|s|^2]
//   via coalesced float4 loads + ds_write_b128.
// blocks [512,1536): knn (cd2 + normal loss) for 16 m each. s=tid&31 n-split,
//   g=tid>>5 owns 2 m-chains. Pts staged in 4x1024-pt phases; phase ph+1 is
//   register-prefetched (6 float4/thread) after the post-staging barrier so
//   the j-loop hides the global latency. Per 2 pairs/chain: 2 add + 6 fma +
//   2 v_and_or + med3 + min + min3 on packed keys (bits(d^2)&~0xFFF)|n
//   (d^2>=0 -> uint order == float order; low 12 bits break ties toward
//   smaller n like top_k). Exact distance recomputed for winners.
__global__ __launch_bounds__(256, 6) void fused_kernel(const float* __restrict__ shape_xyz,
                                                       const float* __restrict__ skel_xyz,
                                                       const float* __restrict__ skel_nori,
                                                       float* __restrict__ out)
{
    __shared__ float4 ls4[1024];   // 16 KB
    __shared__ float ws[4];

    const int tid = threadIdx.x;
    float v = 0.0f;

    if (blockIdx.x < 512) {
        // ================= role 0: cd1 =================
        const int id  = blockIdx.x;
        const int b   = id >> 5;
        const int sub = id & 31;

        // coalesced skel staging: thread t loads float4 3t..3t+2 = pts 4t..4t+3
        const float4* g4 = (const float4*)(skel_xyz + (size_t)b * M_ * 3);
        const float4 r0 = g4[3 * tid + 0];
        const float4 r1 = g4[3 * tid + 1];
        const float4 r2 = g4[3 * tid + 2];

        const int sA = tid & 15;
        const int gA = tid >> 4;
        const int n0 = sub * 128 + gA * 8;
        const float* p = shape_xyz + ((size_t)b * N_ + n0) * 6;
        float m2x[8], m2y[8], m2z[8], pp[8], best[8];
#pragma unroll
        for (int k = 0; k < 8; ++k) {
            const float x = p[k * 6 + 0];
            const float y = p[k * 6 + 1];
            const float z = p[k * 6 + 2];
            m2x[k] = -2.0f * x; m2y[k] = -2.0f * y; m2z[k] = -2.0f * z;
            pp[k]  = fmaf(x, x, fmaf(y, y, z * z));
            best[k] = FLT_MAX;
        }

        {
            float x, y, z;
            x = r0.x; y = r0.y; z = r0.z;
            ls4[4 * tid + 0] = make_float4(x, y, z, fmaf(x, x, fmaf(y, y, z * z)));
            x = r0.w; y = r1.x; z = r1.y;
            ls4[4 * tid + 1] = make_float4(x, y, z, fmaf(x, x, fmaf(y, y, z * z)));
            x = r1.z; y = r1.w; z = r2.x;
            ls4[4 * tid + 2] = make_float4(x, y, z, fmaf(x, x, fmaf(y, y, z * z)));
            x = r2.y; y = r2.z; z = r2.w;
            ls4[4 * tid + 3] = make_float4(x, y, z, fmaf(x, x, fmaf(y, y, z * z)));
        }
        __syncthreads();

#pragma unroll 4
        for (int j = 0; j < 32; ++j) {             // 2 m per iter
            const float4 s0 = ls4[j * 32 + sA];
            const float4 s1 = ls4[j * 32 + 16 + sA];
#pragma unroll
            for (int k = 0; k < 8; ++k) {
                const float t0 = fmaf(m2x[k], s0.x, fmaf(m2y[k], s0.y, fmaf(m2z[k], s0.z, s0.w)));
                const float t1 = fmaf(m2x[k], s1.x, fmaf(m2y[k], s1.y, fmaf(m2z[k], s1.z, s1.w)));
                best[k] = fminf(best[k], fminf(t0, t1));   // -> v_min3_f32
            }
        }

#pragma unroll
        for (int off = 1; off < 16; off <<= 1) {
#pragma unroll
            for (int k = 0; k < 8; ++k) best[k] = fminf(best[k], __shfl_xor(best[k], off));
        }
        if (sA == 0) {
#pragma unroll
            for (int k = 0; k < 8; ++k) v += sqrtf(fmaxf(best[k] + pp[k], EPS_));
            v *= 1e-4f;
        }
    } else {
        // ================= role 1: knn (cd2 + normal loss) =================
        const int id  = blockIdx.x - 512;
        const int b   = id >> 6;
        const int sub = id & 63;
        const int s   = tid & 31;
        const int g   = tid >> 5;                  // 0..7
        const int m0  = sub * 16 + g * 2;          // 2 chains per lane

        float m2x[2], m2y[2], m2z[2], aa[2];
        uint32_t k1[2], k2[2];
        {
            const float* sq = skel_xyz + ((size_t)b * M_ + m0) * 3;
#pragma unroll
            for (int c = 0; c < 2; ++c) {
                const float x = sq[c * 3 + 0];
                const float y = sq[c * 3 + 1];
                const float z = sq[c * 3 + 2];
                m2x[c] = -2.0f * x; m2y[c] = -2.0f * y; m2z[c] = -2.0f * z;
                aa[c]  = fmaf(x, x, fmaf(y, y, z * z));
                k1[c] = 0xFFFFFFFFu; k2[c] = 0xFFFFFFFFu;
            }
        }

        const uint32_t HI = 0xFFFFF000u;
        const float* sb = shape_xyz + (size_t)b * N_ * 6;
        const float4* g4 = (const float4*)sb;

        // prefetch phase 0: thread t holds float4 6t..6t+5 = pts 4t..4t+3
        float4 r[6];
#pragma unroll
        for (int k = 0; k < 6; ++k) r[k] = g4[6 * tid + k];

        for (int ph = 0; ph < 4; ++ph) {
            __syncthreads();                       // previous ls4 contents consumed
            {
                float x, y, z;
                x = r[0].x; y = r[0].y; z = r[0].z;
                ls4[4 * tid + 0] = make_float4(x, y, z, fmaf(x, x, fmaf(y, y, z * z)));
                x = r[1].z; y = r[1].w; z = r[2].x;
                ls4[4 * tid + 1] = make_float4(x, y, z, fmaf(x, x, fmaf(y, y, z * z)));
                x = r[3].x; y = r[3].y; z = r[3].z;
                ls4[4 * tid + 2] = make_float4(x, y, z, fmaf(x, x, fmaf(y, y, z * z)));
                x = r[4].z; y = r[4].w; z = r[5].x;
                ls4[4 * tid + 3] = make_float4(x, y, z, fmaf(x, x, fmaf(y, y, z * z)));
            }
            __syncthreads();
            // issue next phase's loads now; j-loop below hides their latency
            if (ph < 3) {
#pragma unroll
                for (int k = 0; k < 6; ++k) r[k] = g4[(ph + 1) * 1536 + 6 * tid + k];
            }
            const uint32_t nb = (uint32_t)(ph * 1024);

#pragma unroll 4
            for (int j = 0; j < 16; ++j) {         // 2 points per iter
                const float4 q0 = ls4[j * 64 + s];
                const float4 q1 = ls4[j * 64 + 32 + s];
                const uint32_t gn0 = nb + (uint32_t)(j * 64 + s);
                const uint32_t gn1 = gn0 + 32u;
#pragma unroll
                for (int c = 0; c < 2; ++c) {
                    const float t0 = fmaf(m2x[c], q0.x, fmaf(m2y[c], q0.y, fmaf(m2z[c], q0.z, q0.w + aa[c])));
                    const float t1 = fmaf(m2x[c], q1.x, fmaf(m2y[c], q1.y, fmaf(m2z[c], q1.z, q1.w + aa[c])));
                    const uint32_t kk0 = (__float_as_uint(t0) & HI) | gn0;
                    const uint32_t kk1 = (__float_as_uint(t1) & HI) | gn1;
                    k2[c] = min(k2[c], umed3(k1[c], kk0, kk1));
                    k1[c] = umin3(k1[c], kk0, kk1);
                }
            }
        }

        // butterfly top-2 merge across the 32 s-lanes
#pragma unroll
        for (int off = 1; off < 32; off <<= 1) {
#pragma unroll
            for (int c = 0; c < 2; ++c) {
                const uint32_t o1 = (uint32_t)__shfl_xor((int)k1[c], off);
                const uint32_t o2 = (uint32_t)__shfl_xor((int)k2[c], off);
                const uint32_t nk2 = min(min(k2[c], o2), max(k1[c], o1));
                k1[c] = min(k1[c], o1);
                k2[c] = nk2;
            }
        }

        if (s == 0) {
            const float* no = skel_nori + ((size_t)b * M_ + m0) * 3;
            const float kN = 0.001f * 0.5f / (float)B_;
#pragma unroll
            for (int c = 0; c < 2; ++c) {
                const int i1 = (int)(k1[c] & 0xFFFu);
                const int i2 = (int)(k2[c] & 0xFFFu);
                const float* p1 = sb + (size_t)i1 * 6;
                const float* p2 = sb + (size_t)i2 * 6;
                // exact nearest distance (removes key quantization from cd2)
                const float ax = -0.5f * m2x[c], ay = -0.5f * m2y[c], az = -0.5f * m2z[c];
                const float dx = ax - p1[0], dy = ay - p1[1], dz = az - p1[2];
                const float d2 = fmaf(dx, dx, fmaf(dy, dy, dz * dz));
                const float q0 = no[c * 3 + 0], q1 = no[c * 3 + 1], q2 = no[c * 3 + 2];
                const float dot1 = q0 * p1[3] + q1 * p1[4] + q2 * p1[5];
                const float dot2 = q0 * p2[3] + q1 * p2[4] + q2 * p2[5];
                v += sqrtf(fmaxf(d2, EPS_)) * 1e-4f + (fabsf(dot1) + fabsf(dot2)) * kN;
            }
        }
    }

    // block reduction + one atomic per block
#pragma unroll
    for (int off = 32; off > 0; off >>= 1) v += __shfl_down(v, off);
    if ((tid & 63) == 0) ws[tid >> 6] = v;
    __syncthreads();
    if (tid == 0) atomicAdd(out, ws[0] + ws[1] + ws[2] + ws[3]);
}

extern "C" void kernel_launch(void* const* d_in, const int* in_sizes, int n_in,
                              void* d_out, int out_size, void* d_ws, size_t ws_size,
                              hipStream_t stream) {
    const float* shape_xyz = (const float*)d_in[0];  // (16, 4096, 6)
    const float* skel_xyz  = (const float*)d_in[1];  // (16, 1024, 3)
    const float* skel_nori = (const float*)d_in[2];  // (16, 1024, 3)
    float* out = (float*)d_out;                      // scalar

    hipMemsetAsync(out, 0, sizeof(float), stream);   // d_out poisoned each call
    fused_kernel<<<1536, 256, 0, stream>>>(shape_xyz, skel_xyz, skel_nori, out);
}

// Round 8
// 85.345 us; speedup vs baseline: 1.1504x; 1.0248x over previous
//
#include <hip/hip_runtime.h>
#include <cfloat>
#include <stdint.h>

#define B_ 16
#define N_ 4096
#define M_ 1024
#define EPS_ 1e-12f

__device__ __forceinline__ uint32_t umin3(uint32_t a, uint32_t b, uint32_t c) {
    return min(a, min(b, c));                    // -> v_min3_u32
}
__device__ __forceinline__ uint32_t umed3(uint32_t a, uint32_t b, uint32_t c) {
    return max(min(a, b), min(max(a, b), c));    // -> v_med3_u32
}

// 768 blocks = 3/CU exactly, work-matched roles (~3.4-3.6k VALU ops/lane).
// blocks [0,256):   cd1, 256 points each. sA=tid&15 m-split, gA=tid>>4 owns
//   16 points. LDS skel stored pre-doubled (2x,2y,2z,|s|^2) so the pair core
//   is t = fma(-px,2sx, fma(-py,2sy, fma(-pz,2sz, |s|^2))) (3 fma, free neg
//   modifiers) + v_min3_f32 per 2 pairs; |p|^2 added post-min (monotone).
// blocks [256,768): knn (cd2+normal), 32 m each. s=tid&31 n-split, g=tid>>5
//   owns 4 m-chains -> each ds_read_b128 feeds 4 chains. Pts staged in
//   2x2048-pt phases (32 KB); phase 1 register-prefetched (12 float4). Per 2
//   pairs/chain: 2 add + 6 fma + 2 v_and_or + med3 + min + min3 on packed
//   keys (bits(d^2)&~0xFFF)|n (d^2>=0 -> uint order == float order; low 12
//   bits break ties toward smaller n like top_k). Exact distance recomputed
//   for winners in the epilogue.
__global__ __launch_bounds__(256, 3) void fused_kernel(const float* __restrict__ shape_xyz,
                                                       const float* __restrict__ skel_xyz,
                                                       const float* __restrict__ skel_nori,
                                                       float* __restrict__ out)
{
    __shared__ float4 ls4[2048];   // 32 KB
    __shared__ float ws[4];

    const int tid = threadIdx.x;
    float v = 0.0f;

    if (blockIdx.x < 256) {
        // ================= role 0: cd1 =================
        const int b    = blockIdx.x >> 4;      // 16 tiles per b
        const int tile = blockIdx.x & 15;

        // stage skel: thread t loads float4 3t..3t+2 = pts 4t..4t+3
        const float4* g4 = (const float4*)(skel_xyz + (size_t)b * M_ * 3);
        const float4 r0 = g4[3 * tid + 0];
        const float4 r1 = g4[3 * tid + 1];
        const float4 r2 = g4[3 * tid + 2];

        const int sA = tid & 15;
        const int gA = tid >> 4;
        const int n0 = tile * 256 + gA * 16;
        const float* p = shape_xyz + ((size_t)b * N_ + n0) * 6;
        float px[16], py[16], pz[16], pp[16], best[16];
#pragma unroll
        for (int k = 0; k < 16; ++k) {
            px[k] = p[k * 6 + 0];
            py[k] = p[k * 6 + 1];
            pz[k] = p[k * 6 + 2];
            pp[k] = fmaf(px[k], px[k], fmaf(py[k], py[k], pz[k] * pz[k]));
            best[k] = FLT_MAX;
        }

        {
            float x, y, z;
            x = r0.x; y = r0.y; z = r0.z;
            ls4[4 * tid + 0] = make_float4(2*x, 2*y, 2*z, fmaf(x, x, fmaf(y, y, z * z)));
            x = r0.w; y = r1.x; z = r1.y;
            ls4[4 * tid + 1] = make_float4(2*x, 2*y, 2*z, fmaf(x, x, fmaf(y, y, z * z)));
            x = r1.z; y = r1.w; z = r2.x;
            ls4[4 * tid + 2] = make_float4(2*x, 2*y, 2*z, fmaf(x, x, fmaf(y, y, z * z)));
            x = r2.y; y = r2.z; z = r2.w;
            ls4[4 * tid + 3] = make_float4(2*x, 2*y, 2*z, fmaf(x, x, fmaf(y, y, z * z)));
        }
        __syncthreads();

#pragma unroll 2
        for (int j = 0; j < 32; ++j) {             // 2 m per iter
            const float4 s0 = ls4[j * 32 + sA];
            const float4 s1 = ls4[j * 32 + 16 + sA];
#pragma unroll
            for (int k = 0; k < 16; ++k) {
                const float t0 = fmaf(-px[k], s0.x, fmaf(-py[k], s0.y, fmaf(-pz[k], s0.z, s0.w)));
                const float t1 = fmaf(-px[k], s1.x, fmaf(-py[k], s1.y, fmaf(-pz[k], s1.z, s1.w)));
                best[k] = fminf(best[k], fminf(t0, t1));   // -> v_min3_f32
            }
        }

#pragma unroll
        for (int off = 1; off < 16; off <<= 1) {
#pragma unroll
            for (int k = 0; k < 16; ++k) best[k] = fminf(best[k], __shfl_xor(best[k], off));
        }
        if (sA == 0) {
#pragma unroll
            for (int k = 0; k < 16; ++k) v += sqrtf(fmaxf(best[k] + pp[k], EPS_));
            v *= 1e-4f;
        }
    } else {
        // ================= role 1: knn (cd2 + normal loss) =================
        const int id  = blockIdx.x - 256;
        const int b   = id >> 5;                   // 32 blocks per b
        const int sub = id & 31;
        const int s   = tid & 31;
        const int g   = tid >> 5;                  // 0..7
        const int m0  = sub * 32 + g * 4;          // 4 chains per lane

        float m2x[4], m2y[4], m2z[4], aa[4];
        uint32_t k1[4], k2[4];
        {
            const float* sq = skel_xyz + ((size_t)b * M_ + m0) * 3;
#pragma unroll
            for (int c = 0; c < 4; ++c) {
                const float x = sq[c * 3 + 0];
                const float y = sq[c * 3 + 1];
                const float z = sq[c * 3 + 2];
                m2x[c] = -2.0f * x; m2y[c] = -2.0f * y; m2z[c] = -2.0f * z;
                aa[c]  = fmaf(x, x, fmaf(y, y, z * z));
                k1[c] = 0xFFFFFFFFu; k2[c] = 0xFFFFFFFFu;
            }
        }

        const uint32_t HI = 0xFFFFF000u;
        const float* sb = shape_xyz + (size_t)b * N_ * 6;
        const float4* g4 = (const float4*)sb;

        // prefetch phase 0: thread t holds float4 12t..12t+11 = pts 8t..8t+7
        float4 r[12];
#pragma unroll
        for (int k = 0; k < 12; ++k) r[k] = g4[12 * tid + k];

        for (int ph = 0; ph < 2; ++ph) {
            __syncthreads();                       // previous ls4 contents consumed
#pragma unroll
            for (int i = 0; i < 4; ++i) {          // pts 8t+2i, 8t+2i+1
                float x, y, z;
                x = r[3 * i].x; y = r[3 * i].y; z = r[3 * i].z;
                ls4[8 * tid + 2 * i + 0] = make_float4(x, y, z, fmaf(x, x, fmaf(y, y, z * z)));
                x = r[3 * i + 1].z; y = r[3 * i + 1].w; z = r[3 * i + 2].x;
                ls4[8 * tid + 2 * i + 1] = make_float4(x, y, z, fmaf(x, x, fmaf(y, y, z * z)));
            }
            __syncthreads();
            // issue next phase's loads now; j-loop below hides their latency
            if (ph == 0) {
#pragma unroll
                for (int k = 0; k < 12; ++k) r[k] = g4[3072 + 12 * tid + k];
            }
            const uint32_t nb = (uint32_t)(ph * 2048);

#pragma unroll 4
            for (int j = 0; j < 32; ++j) {         // 2 points per iter
                const int nl = j * 64 + s;
                const float4 q0 = ls4[nl];
                const float4 q1 = ls4[nl + 32];
                const uint32_t gn0 = nb + (uint32_t)nl;
                const uint32_t gn1 = gn0 + 32u;
#pragma unroll
                for (int c = 0; c < 4; ++c) {
                    const float t0 = fmaf(m2x[c], q0.x, fmaf(m2y[c], q0.y, fmaf(m2z[c], q0.z, q0.w + aa[c])));
                    const float t1 = fmaf(m2x[c], q1.x, fmaf(m2y[c], q1.y, fmaf(m2z[c], q1.z, q1.w + aa[c])));
                    const uint32_t kk0 = (__float_as_uint(t0) & HI) | gn0;
                    const uint32_t kk1 = (__float_as_uint(t1) & HI) | gn1;
                    k2[c] = min(k2[c], umed3(k1[c], kk0, kk1));
                    k1[c] = umin3(k1[c], kk0, kk1);
                }
            }
        }

        // butterfly top-2 merge across the 32 s-lanes
#pragma unroll
        for (int off = 1; off < 32; off <<= 1) {
#pragma unroll
            for (int c = 0; c < 4; ++c) {
                const uint32_t o1 = (uint32_t)__shfl_xor((int)k1[c], off);
                const uint32_t o2 = (uint32_t)__shfl_xor((int)k2[c], off);
                const uint32_t nk2 = min(min(k2[c], o2), max(k1[c], o1));
                k1[c] = min(k1[c], o1);
                k2[c] = nk2;
            }
        }

        if (s == 0) {
            const float* no = skel_nori + ((size_t)b * M_ + m0) * 3;
            const float kN = 0.001f * 0.5f / (float)B_;
#pragma unroll
            for (int c = 0; c < 4; ++c) {
                const int i1 = (int)(k1[c] & 0xFFFu);
                const int i2 = (int)(k2[c] & 0xFFFu);
                const float* p1 = sb + (size_t)i1 * 6;
                const float* p2 = sb + (size_t)i2 * 6;
                // exact nearest distance (removes key quantization from cd2)
                const float ax = -0.5f * m2x[c], ay = -0.5f * m2y[c], az = -0.5f * m2z[c];
                const float dx = ax - p1[0], dy = ay - p1[1], dz = az - p1[2];
                const float d2 = fmaf(dx, dx, fmaf(dy, dy, dz * dz));
                const float q0 = no[c * 3 + 0], q1 = no[c * 3 + 1], q2 = no[c * 3 + 2];
                const float dot1 = q0 * p1[3] + q1 * p1[4] + q2 * p1[5];
                const float dot2 = q0 * p2[3] + q1 * p2[4] + q2 * p2[5];
                v += sqrtf(fmaxf(d2, EPS_)) * 1e-4f + (fabsf(dot1) + fabsf(dot2)) * kN;
            }
        }
    }

    // block reduction + one atomic per block
#pragma unroll
    for (int off = 32; off > 0; off >>= 1) v += __shfl_down(v, off);
    if ((tid & 63) == 0) ws[tid >> 6] = v;
    __syncthreads();
    if (tid == 0) atomicAdd(out, ws[0] + ws[1] + ws[2] + ws[3]);
}

extern "C" void kernel_launch(void* const* d_in, const int* in_sizes, int n_in,
                              void* d_out, int out_size, void* d_ws, size_t ws_size,
                              hipStream_t stream) {
    const float* shape_xyz = (const float*)d_in[0];  // (16, 4096, 6)
    const float* skel_xyz  = (const float*)d_in[1];  // (16, 1024, 3)
    const float* skel_nori = (const float*)d_in[2];  // (16, 1024, 3)
    float* out = (float*)d_out;                      // scalar

    hipMemsetAsync(out, 0, sizeof(float), stream);   // d_out poisoned each call
    fused_kernel<<<768, 256, 0, stream>>>(shape_xyz, skel_xyz, skel_nori, out);
}

// Round 9
// 83.398 us; speedup vs baseline: 1.1773x; 1.0233x over previous
//
#include <hip/hip_runtime.h>
#include <cfloat>
#include <stdint.h>

#define B_ 16
#define N_ 4096
#define M_ 1024
#define EPS_ 1e-12f

typedef float v2f __attribute__((ext_vector_type(2)));

__device__ __forceinline__ v2f fma2(v2f a, v2f b, v2f c) {
    return __builtin_elementwise_fma(a, b, c);     // -> v_pk_fma_f32
}
__device__ __forceinline__ v2f splat(float x) { return (v2f){x, x}; }

__device__ __forceinline__ uint32_t umin3(uint32_t a, uint32_t b, uint32_t c) {
    return min(a, min(b, c));                      // -> v_min3_u32
}
__device__ __forceinline__ uint32_t umed3(uint32_t a, uint32_t b, uint32_t c) {
    return max(min(a, b), min(max(a, b), c));      // -> v_med3_u32
}

// 768 blocks = 3/CU exactly, work-matched roles. Both hot loops use packed
// fp32 (v_pk_fma_f32) on pairs delivered by ds_read2_b32 from SoA LDS.
// blocks [0,256):   cd1, 256 pts each; sA=tid&15 m-split, gA=tid>>4 owns 16
//   pts. Pair = (m, m+16). Per pt per 2-m: 3 pk_fma + v_min3_f32 on
//   t = |s|^2 - 2 p.s (|p|^2 added post-min; monotone).
// blocks [256,768): knn (cd2+normal), 32 m each; s=tid&31 n-split, g=tid>>5
//   owns 4 chains. Pair = (n, n+32). 2 staging phases of 2048 pts (32 KB),
//   phase 1 register-prefetched. Per chain per 2 pts: pk_add + 3 pk_fma +
//   2 v_and_or + med3 + min + min3 on packed keys (bits(d^2)&~0xFFF)|n
//   (d^2>=0 -> uint order == float order; low 12 bits break ties toward
//   smaller n like top_k). Exact distance recomputed for winners.
__global__ __launch_bounds__(256, 3) void fused_kernel(const float* __restrict__ shape_xyz,
                                                       const float* __restrict__ skel_xyz,
                                                       const float* __restrict__ skel_nori,
                                                       float* __restrict__ out)
{
    __shared__ float ls[8192];     // 32 KB, SoA; role-dependent partitioning
    __shared__ float ws[4];

    const int tid = threadIdx.x;
    float v = 0.0f;

    if (blockIdx.x < 256) {
        // ================= role 0: cd1 =================
        const int b    = blockIdx.x >> 4;
        const int tile = blockIdx.x & 15;
        float* lsx = ls;
        float* lsy = ls + 1024;
        float* lsz = ls + 2048;
        float* lsw = ls + 3072;

        // coalesced skel staging: thread t loads float4 3t..3t+2 = pts 4t..4t+3
        const float4* g4 = (const float4*)(skel_xyz + (size_t)b * M_ * 3);
        const float4 r0 = g4[3 * tid + 0];
        const float4 r1 = g4[3 * tid + 1];
        const float4 r2 = g4[3 * tid + 2];

        const int sA = tid & 15;
        const int gA = tid >> 4;
        const int n0 = tile * 256 + gA * 16;
        const float* p = shape_xyz + ((size_t)b * N_ + n0) * 6;
        float nx[16], ny[16], nz[16], best[16];
#pragma unroll
        for (int k = 0; k < 16; ++k) {
            nx[k] = -p[k * 6 + 0];
            ny[k] = -p[k * 6 + 1];
            nz[k] = -p[k * 6 + 2];
            best[k] = FLT_MAX;
        }

        {
            const float4 X = make_float4(2*r0.x, 2*r0.w, 2*r1.z, 2*r2.y);
            const float4 Y = make_float4(2*r0.y, 2*r1.x, 2*r1.w, 2*r2.z);
            const float4 Z = make_float4(2*r0.z, 2*r1.y, 2*r2.x, 2*r2.w);
            const float4 W = make_float4(
                fmaf(r0.x, r0.x, fmaf(r0.y, r0.y, r0.z * r0.z)),
                fmaf(r0.w, r0.w, fmaf(r1.x, r1.x, r1.y * r1.y)),
                fmaf(r1.z, r1.z, fmaf(r1.w, r1.w, r2.x * r2.x)),
                fmaf(r2.y, r2.y, fmaf(r2.z, r2.z, r2.w * r2.w)));
            *(float4*)&lsx[4 * tid] = X;
            *(float4*)&lsy[4 * tid] = Y;
            *(float4*)&lsz[4 * tid] = Z;
            *(float4*)&lsw[4 * tid] = W;
        }
        __syncthreads();

#pragma unroll 2
        for (int j = 0; j < 32; ++j) {             // pair (m, m+16) per iter
            const int m = j * 32 + sA;
            const v2f sx = {lsx[m], lsx[m + 16]};  // -> ds_read2_b32
            const v2f sy = {lsy[m], lsy[m + 16]};
            const v2f sz = {lsz[m], lsz[m + 16]};
            const v2f sw = {lsw[m], lsw[m + 16]};
#pragma unroll
            for (int k = 0; k < 16; ++k) {
                const v2f t = fma2(splat(nx[k]), sx,
                              fma2(splat(ny[k]), sy,
                              fma2(splat(nz[k]), sz, sw)));
                best[k] = fminf(best[k], fminf(t.x, t.y));   // -> v_min3_f32
            }
        }

#pragma unroll
        for (int off = 1; off < 16; off <<= 1) {
#pragma unroll
            for (int k = 0; k < 16; ++k) best[k] = fminf(best[k], __shfl_xor(best[k], off));
        }
        if (sA == 0) {
#pragma unroll
            for (int k = 0; k < 16; ++k) {
                const float pp = fmaf(nx[k], nx[k], fmaf(ny[k], ny[k], nz[k] * nz[k]));
                v += sqrtf(fmaxf(best[k] + pp, EPS_));
            }
            v *= 1e-4f;
        }
    } else {
        // ================= role 1: knn (cd2 + normal loss) =================
        const int id  = blockIdx.x - 256;
        const int b   = id >> 5;
        const int sub = id & 31;
        const int s   = tid & 31;
        const int g   = tid >> 5;                  // 0..7
        const int m0  = sub * 32 + g * 4;          // 4 chains per lane
        float* lsx = ls;
        float* lsy = ls + 2048;
        float* lsz = ls + 4096;
        float* lsw = ls + 6144;

        float m2x[4], m2y[4], m2z[4], aa[4];
        uint32_t k1[4], k2[4];
        {
            const float* sq = skel_xyz + ((size_t)b * M_ + m0) * 3;
#pragma unroll
            for (int c = 0; c < 4; ++c) {
                const float x = sq[c * 3 + 0];
                const float y = sq[c * 3 + 1];
                const float z = sq[c * 3 + 2];
                m2x[c] = -2.0f * x; m2y[c] = -2.0f * y; m2z[c] = -2.0f * z;
                aa[c]  = fmaf(x, x, fmaf(y, y, z * z));
                k1[c] = 0xFFFFFFFFu; k2[c] = 0xFFFFFFFFu;
            }
        }

        const uint32_t HI = 0xFFFFF000u;
        const float* sb = shape_xyz + (size_t)b * N_ * 6;
        const float4* g4 = (const float4*)sb;

        // prefetch phase 0: thread t holds float4 12t..12t+11 = pts 8t..8t+7
        float4 r[12];
#pragma unroll
        for (int k = 0; k < 12; ++k) r[k] = g4[12 * tid + k];

        for (int ph = 0; ph < 2; ++ph) {
            __syncthreads();                       // previous ls contents consumed
#pragma unroll
            for (int h = 0; h < 2; ++h) {          // pts 8t+4h .. 8t+4h+3
                const float4 a0 = r[6 * h + 0], a1 = r[6 * h + 1], a2 = r[6 * h + 2];
                const float4 a3 = r[6 * h + 3], a4 = r[6 * h + 4], a5 = r[6 * h + 5];
                const float4 X = make_float4(a0.x, a1.z, a3.x, a4.z);
                const float4 Y = make_float4(a0.y, a1.w, a3.y, a4.w);
                const float4 Z = make_float4(a0.z, a2.x, a3.z, a5.x);
                const float4 W = make_float4(
                    fmaf(X.x, X.x, fmaf(Y.x, Y.x, Z.x * Z.x)),
                    fmaf(X.y, X.y, fmaf(Y.y, Y.y, Z.y * Z.y)),
                    fmaf(X.z, X.z, fmaf(Y.z, Y.z, Z.z * Z.z)),
                    fmaf(X.w, X.w, fmaf(Y.w, Y.w, Z.w * Z.w)));
                *(float4*)&lsx[8 * tid + 4 * h] = X;
                *(float4*)&lsy[8 * tid + 4 * h] = Y;
                *(float4*)&lsz[8 * tid + 4 * h] = Z;
                *(float4*)&lsw[8 * tid + 4 * h] = W;
            }
            __syncthreads();
            // issue next phase's loads now; j-loop below hides their latency
            if (ph == 0) {
#pragma unroll
                for (int k = 0; k < 12; ++k) r[k] = g4[3072 + 12 * tid + k];
            }
            const uint32_t nb = (uint32_t)(ph * 2048);

#pragma unroll 4
            for (int j = 0; j < 32; ++j) {         // pair (n, n+32) per iter
                const int nl = j * 64 + s;
                const v2f qx = {lsx[nl], lsx[nl + 32]};   // -> ds_read2_b32
                const v2f qy = {lsy[nl], lsy[nl + 32]};
                const v2f qz = {lsz[nl], lsz[nl + 32]};
                const v2f qw = {lsw[nl], lsw[nl + 32]};
                const uint32_t gn0 = nb + (uint32_t)nl;
                const uint32_t gn1 = gn0 + 32u;
#pragma unroll
                for (int c = 0; c < 4; ++c) {
                    const v2f t = fma2(splat(m2x[c]), qx,
                                  fma2(splat(m2y[c]), qy,
                                  fma2(splat(m2z[c]), qz, qw + splat(aa[c]))));
                    const uint32_t kk0 = (__float_as_uint(t.x) & HI) | gn0;
                    const uint32_t kk1 = (__float_as_uint(t.y) & HI) | gn1;
                    k2[c] = min(k2[c], umed3(k1[c], kk0, kk1));
                    k1[c] = umin3(k1[c], kk0, kk1);
                }
            }
        }

        // butterfly top-2 merge across the 32 s-lanes
#pragma unroll
        for (int off = 1; off < 32; off <<= 1) {
#pragma unroll
            for (int c = 0; c < 4; ++c) {
                const uint32_t o1 = (uint32_t)__shfl_xor((int)k1[c], off);
                const uint32_t o2 = (uint32_t)__shfl_xor((int)k2[c], off);
                const uint32_t nk2 = min(min(k2[c], o2), max(k1[c], o1));
                k1[c] = min(k1[c], o1);
                k2[c] = nk2;
            }
        }

        if (s == 0) {
            const float* no = skel_nori + ((size_t)b * M_ + m0) * 3;
            const float kN = 0.001f * 0.5f / (float)B_;
#pragma unroll
            for (int c = 0; c < 4; ++c) {
                const int i1 = (int)(k1[c] & 0xFFFu);
                const int i2 = (int)(k2[c] & 0xFFFu);
                const float* p1 = sb + (size_t)i1 * 6;
                const float* p2 = sb + (size_t)i2 * 6;
                // exact nearest distance (removes key quantization from cd2)
                const float ax = -0.5f * m2x[c], ay = -0.5f * m2y[c], az = -0.5f * m2z[c];
                const float dx = ax - p1[0], dy = ay - p1[1], dz = az - p1[2];
                const float d2 = fmaf(dx, dx, fmaf(dy, dy, dz * dz));
                const float q0 = no[c * 3 + 0], q1 = no[c * 3 + 1], q2 = no[c * 3 + 2];
                const float dot1 = q0 * p1[3] + q1 * p1[4] + q2 * p1[5];
                const float dot2 = q0 * p2[3] + q1 * p2[4] + q2 * p2[5];
                v += sqrtf(fmaxf(d2, EPS_)) * 1e-4f + (fabsf(dot1) + fabsf(dot2)) * kN;
            }
        }
    }

    // block reduction + one atomic per block
#pragma unroll
    for (int off = 32; off > 0; off >>= 1) v += __shfl_down(v, off);
    if ((tid & 63) == 0) ws[tid >> 6] = v;
    __syncthreads();
    if (tid == 0) atomicAdd(out, ws[0] + ws[1] + ws[2] + ws[3]);
}

extern "C" void kernel_launch(void* const* d_in, const int* in_sizes, int n_in,
                              void* d_out, int out_size, void* d_ws, size_t ws_size,
                              hipStream_t stream) {
    const float* shape_xyz = (const float*)d_in[0];  // (16, 4096, 6)
    const float* skel_xyz  = (const float*)d_in[1];  // (16, 1024, 3)
    const float* skel_nori = (const float*)d_in[2];  // (16, 1024, 3)
    float* out = (float*)d_out;                      // scalar

    hipMemsetAsync(out, 0, sizeof(float), stream);   // d_out poisoned each call
    fused_kernel<<<768, 256, 0, stream>>>(shape_xyz, skel_xyz, skel_nori, out);
}